// Round 12
// baseline (64.184 us; speedup 1.0000x reference)
//
#include <hip/hip_runtime.h>

#define NN 50000
#define TT 12
#define QQ 3
#define HH 64
#define KK 32
#define TQ 36    // T*Q
#define PW 9     // 8-byte words per row (72 B = 9 x uint2); thread = (node, p<9)
#define NLEV 4

// State = XW = out*scaler, bf16, packed 4 elements per uint2. Level recursion
// in XW-space is a pure gather-sum (scaler cancels). R11 proved: bf16 rows
// (72B = 2 sectors vs fp32 3) + all-gathers-in-flight wins. R12 tests the
// issue-bound hypothesis: dwordx2 gathers halve instruction count & waves.
__device__ __forceinline__ float bf2f(unsigned int u16) {
    union { unsigned int i; float f; } c; c.i = u16 << 16; return c.f;
}
__device__ __forceinline__ unsigned short f2bf(float f) {
    union { float f; unsigned int i; } c; c.f = f;
    unsigned int u = c.i;
    u += 0x7FFFu + ((u >> 16) & 1u);
    return (unsigned short)(u >> 16);
}

// ---------------------------------------------------------------------------
// Projection in XW-space (bf16 out): xw[row*3+q] = (proj+b)[row,q] * sc[row].
// ---------------------------------------------------------------------------
__global__ __launch_bounds__(256) void proj_xw_kernel(
    const float* __restrict__ gnn, const float* __restrict__ w,
    const float* __restrict__ b, const float* __restrict__ scaler,
    unsigned short* __restrict__ xw, int nrows)
{
    const int lane = threadIdx.x & 63;
    const int sub  = lane & 15;
    const int h0   = sub * 4;

    float wreg[4][3];
#pragma unroll
    for (int j = 0; j < 4; ++j)
#pragma unroll
        for (int q = 0; q < 3; ++q)
            wreg[j][q] = w[(h0 + j) * 3 + q];
    const float b0 = b[0], b1 = b[1], b2 = b[2];

    const int gwave  = (blockIdx.x * blockDim.x + threadIdx.x) >> 6;
    const int nwaves = (gridDim.x * blockDim.x) >> 6;
    const int nquads = nrows >> 2;

    for (int quad = gwave; quad < nquads; quad += nwaves) {
        const float4 g = *reinterpret_cast<const float4*>(gnn + (size_t)quad * 256 + lane * 4);
        float a0 = g.x * wreg[0][0] + g.y * wreg[1][0] + g.z * wreg[2][0] + g.w * wreg[3][0];
        float a1 = g.x * wreg[0][1] + g.y * wreg[1][1] + g.z * wreg[2][1] + g.w * wreg[3][1];
        float a2 = g.x * wreg[0][2] + g.y * wreg[1][2] + g.z * wreg[2][2] + g.w * wreg[3][2];
#pragma unroll
        for (int off = 8; off > 0; off >>= 1) {
            a0 += __shfl_down(a0, off);
            a1 += __shfl_down(a1, off);
            a2 += __shfl_down(a2, off);
        }
        if (sub == 0) {
            const int row = quad * 4 + (lane >> 4);   // row = node*T + t
            const float s = scaler[row];
            xw[row * 3 + 0] = f2bf((a0 + b0) * s);
            xw[row * 3 + 1] = f2bf((a1 + b1) * s);
            xw[row * 3 + 2] = f2bf((a2 + b2) * s);
        }
    }
}

// ---------------------------------------------------------------------------
// Gather-sum for one uint2 (4 bf16 elements): 32 dwordx2 gathers all in
// flight (keys preloaded via 8x int4), convert+accumulate afterwards.
// ---------------------------------------------------------------------------
__device__ __forceinline__ float4 gather_sum_quad(
    const uint2* __restrict__ cur64, const int* __restrict__ keybom,
    int node, int p)
{
    const int4* kb4 = reinterpret_cast<const int4*>(keybom + (size_t)node * KK);
    int keys[KK];
#pragma unroll
    for (int kk = 0; kk < KK / 4; ++kk) {
        const int4 k4 = kb4[kk];
        keys[kk * 4 + 0] = k4.x;
        keys[kk * 4 + 1] = k4.y;
        keys[kk * 4 + 2] = k4.z;
        keys[kk * 4 + 3] = k4.w;
    }
    uint2 u[KK];
#pragma unroll
    for (int k = 0; k < KK; ++k) {
        const int key = keys[k];
        u[k] = (key >= 0) ? cur64[(size_t)key * PW + p] : make_uint2(0u, 0u);
    }
    float a0 = 0.f, a1 = 0.f, a2 = 0.f, a3 = 0.f;
#pragma unroll
    for (int k = 0; k < KK; ++k) {
        a0 += bf2f(u[k].x & 0xFFFFu);
        a1 += bf2f(u[k].x >> 16);
        a2 += bf2f(u[k].y & 0xFFFFu);
        a3 += bf2f(u[k].y >> 16);
    }
    return make_float4(a0, a1, a2, a3);
}

// ---------------------------------------------------------------------------
// One level in XW-space, ping-pong. Thread = (node, p<9) owns 4 elements.
// ---------------------------------------------------------------------------
__global__ __launch_bounds__(256) void level_kernel(
    const uint2* __restrict__ cur64, const int* __restrict__ keybom,
    const int* __restrict__ lvl, uint2* __restrict__ nxt64, int level)
{
    const int idx  = blockIdx.x * blockDim.x + threadIdx.x;
    if (idx >= NN * PW) return;
    const int node = idx / PW;
    const int p    = idx - node * PW;

    if (lvl[node] != level) {                 // pass-through: 8B copy
        nxt64[idx] = cur64[idx];
        return;
    }
    const float4 s = gather_sum_quad(cur64, keybom, node, p);
    nxt64[idx] = make_uint2(
        (unsigned int)f2bf(s.x) | ((unsigned int)f2bf(s.y) << 16),
        (unsigned int)f2bf(s.z) | ((unsigned int)f2bf(s.w) << 16));
}

// ---------------------------------------------------------------------------
// Final level fused with XW -> out: out = XW / scaler, fp32, float4 store
// (elements 4p..4p+3 of the node's 36-element row; 16B-aligned).
// ---------------------------------------------------------------------------
__global__ __launch_bounds__(256) void level_final_kernel(
    const uint2* __restrict__ cur64, const float* __restrict__ scaler,
    const int* __restrict__ keybom, const int* __restrict__ lvl,
    float* __restrict__ out, int level)
{
    const int idx  = blockIdx.x * blockDim.x + threadIdx.x;
    if (idx >= NN * PW) return;
    const int node = idx / PW;
    const int p    = idx - node * PW;

    float4 v;
    if (lvl[node] != level) {
        const uint2 u = cur64[idx];
        v = make_float4(bf2f(u.x & 0xFFFFu), bf2f(u.x >> 16),
                        bf2f(u.y & 0xFFFFu), bf2f(u.y >> 16));
    } else {
        v = gather_sum_quad(cur64, keybom, node, p);
    }
    const int e0 = node * TQ + 4 * p;
    const float4 r = make_float4(v.x / scaler[(e0 + 0) / 3],
                                 v.y / scaler[(e0 + 1) / 3],
                                 v.z / scaler[(e0 + 2) / 3],
                                 v.w / scaler[(e0 + 3) / 3]);
    *reinterpret_cast<float4*>(out + e0) = r;   // 144n + 16p: 16B-aligned
}

extern "C" void kernel_launch(void* const* d_in, const int* in_sizes, int n_in,
                              void* d_out, int out_size, void* d_ws, size_t ws_size,
                              hipStream_t stream)
{
    const float* gnn    = (const float*)d_in[0];
    const float* w      = (const float*)d_in[1];
    const float* b      = (const float*)d_in[2];
    const float* scaler = (const float*)d_in[3];
    const int*   keybom = (const int*)d_in[4];
    const int*   lvl    = (const int*)d_in[5];
    float* out = (float*)d_out;

    char* ws = (char*)d_ws;
    unsigned short* bufA = (unsigned short*)ws;                         // 3.6 MB
    unsigned short* bufB = (unsigned short*)(ws + (size_t)NN * TQ * 2); // 3.6 MB

    proj_xw_kernel<<<2048, 256, 0, stream>>>(gnn, w, b, scaler, bufA, NN * TT);

    const int blocks = (NN * PW + 255) / 256;
    level_kernel<<<blocks, 256, 0, stream>>>((const uint2*)bufA, keybom, lvl,
                                             (uint2*)bufB, 1);
    level_kernel<<<blocks, 256, 0, stream>>>((const uint2*)bufB, keybom, lvl,
                                             (uint2*)bufA, 2);
    level_final_kernel<<<blocks, 256, 0, stream>>>((const uint2*)bufA, scaler,
                                                   keybom, lvl, out, 3);
}